// Round 6
// baseline (2627.080 us; speedup 1.0000x reference)
//
#include <hip/hip_runtime.h>
#include <math.h>

#define VOCAB 100000
#define BATCH 4096
#define DOC_LEN 200
#define EMBED_DIM 300
#define NUM_CLASSES 20

// ---------------------------------------------------------------------------
// Kernel 1:  P[v][c] = sum_k emb[v][k] * (W[c][k]/DOC_LEN)
// Round-1's proven shape (thread = 1 row x all 20 classes; W broadcast from
// LDS; each emb element read exactly once) with R=1 for 2x the waves (1563,
// ~6/CU) and a small register footprint (~76 live: 20 acc + 9 staged float4
// + W quads) that stays far from the 128-VGPR spill cliff that killed the
// K-split designs (rounds 2/5). Explicit 2-chunk-ahead pipeline keeps 9 KB
// of loads in flight per wave so HBM BW does not depend on occupancy.
// ---------------------------------------------------------------------------
#define K1_BLOCK 128
#define K1_GRID  ((VOCAB + K1_BLOCK - 1) / K1_BLOCK)   // 782

__global__ __launch_bounds__(K1_BLOCK) void project_kernel(
    const float* __restrict__ emb,   // (VOCAB, 300)
    const float* __restrict__ W,     // (20, 300)
    float*       __restrict__ P)     // (VOCAB, 20)  [workspace]
{
    __shared__ float sWT[EMBED_DIM][NUM_CLASSES];   // 24000 B, k-major

    const float inv = 1.0f / (float)DOC_LEN;
    for (int i = threadIdx.x; i < NUM_CLASSES * EMBED_DIM; i += K1_BLOCK) {
        const int c = i / EMBED_DIM;
        const int k = i - c * EMBED_DIM;
        sWT[k][c] = W[i] * inv;                     // fold mean into W
    }
    __syncthreads();

    const int row  = blockIdx.x * K1_BLOCK + threadIdx.x;
    const int rrow = row < VOCAB ? row : VOCAB - 1;     // clamp reads only
    const float* __restrict__ e = emb + (size_t)rrow * EMBED_DIM;

    float acc[NUM_CLASSES];
    #pragma unroll
    for (int c = 0; c < NUM_CLASSES; ++c) acc[c] = 0.0f;

    // 300 dims = 25 chunks of 12 floats; explicit 2-ahead load pipeline.
    float4 p0a = *reinterpret_cast<const float4*>(e + 0);
    float4 p0b = *reinterpret_cast<const float4*>(e + 4);
    float4 p0c = *reinterpret_cast<const float4*>(e + 8);
    float4 p1a = *reinterpret_cast<const float4*>(e + 12);
    float4 p1b = *reinterpret_cast<const float4*>(e + 16);
    float4 p1c = *reinterpret_cast<const float4*>(e + 20);

    #pragma unroll
    for (int kk = 0; kk < 25; ++kk) {
        float4 ta, tb, tc;
        if (kk < 23) {                                  // prefetch chunk kk+2
            const int nk = 12 * (kk + 2);
            ta = *reinterpret_cast<const float4*>(e + nk);
            tb = *reinterpret_cast<const float4*>(e + nk + 4);
            tc = *reinterpret_cast<const float4*>(e + nk + 8);
        }

        const int k = 12 * kk;
        const float* aq = &p0a.x;                       // 12 current values
        #pragma unroll
        for (int j = 0; j < 12; ++j) {
            const float av = aq[j];                     // all float4s contiguous? no:
            // (p0a,p0b,p0c are separate vars; index via explicit selection)
            (void)av;
        }
        // process the 12 k-values of the current chunk explicitly
        const float cur[12] = { p0a.x, p0a.y, p0a.z, p0a.w,
                                p0b.x, p0b.y, p0b.z, p0b.w,
                                p0c.x, p0c.y, p0c.z, p0c.w };
        #pragma unroll
        for (int j = 0; j < 12; ++j) {
            const float av = cur[j];
            const int   kw = k + j;
            #pragma unroll
            for (int c4 = 0; c4 < NUM_CLASSES; c4 += 4) {
                const float4 w = *reinterpret_cast<const float4*>(&sWT[kw][c4]);
                acc[c4 + 0] += av * w.x;
                acc[c4 + 1] += av * w.y;
                acc[c4 + 2] += av * w.z;
                acc[c4 + 3] += av * w.w;
            }
        }

        // rotate pipeline
        p0a = p1a; p0b = p1b; p0c = p1c;
        if (kk < 23) { p1a = ta; p1b = tb; p1c = tc; }
    }

    if (row < VOCAB) {
        float* p = P + (size_t)row * NUM_CLASSES;
        #pragma unroll
        for (int c4 = 0; c4 < NUM_CLASSES; c4 += 4) {
            const float4 v = make_float4(acc[c4], acc[c4 + 1],
                                         acc[c4 + 2], acc[c4 + 3]);
            *reinterpret_cast<float4*>(p + c4) = v;
        }
    }
}

// ---------------------------------------------------------------------------
// Kernel 2: out[doc] = softmax( sum_l P[x[doc][l]] + b )   (unchanged)
// One wave per doc; 64 lanes = 3 position-groups x 20 classes.
// ---------------------------------------------------------------------------
#define K2_BLOCK 256
#define DOCS_PER_BLOCK 4

__global__ __launch_bounds__(K2_BLOCK) void pool_softmax_kernel(
    const float* __restrict__ P,     // (VOCAB, 20), pre-scaled by 1/DOC_LEN
    const float* __restrict__ bias,  // (20,)
    const int*   __restrict__ x,     // (BATCH, 200)
    float*       __restrict__ out)   // (BATCH, 20)
{
    __shared__ int sidx[DOCS_PER_BLOCK][DOC_LEN];

    const int doc0 = blockIdx.x * DOCS_PER_BLOCK;
    const int tid  = threadIdx.x;

    for (int i = tid; i < DOCS_PER_BLOCK * DOC_LEN; i += K2_BLOCK)
        (&sidx[0][0])[i] = x[doc0 * DOC_LEN + i];
    __syncthreads();

    const int wave = tid >> 6;
    const int lane = tid & 63;
    const int doc  = doc0 + wave;
    const int g    = lane / NUM_CLASSES;          // 0..2 active, 3 idle
    const int c    = lane - g * NUM_CLASSES;

    float acc = 0.0f;
    if (g < 3) {
        #pragma unroll 4
        for (int l = g; l < DOC_LEN; l += 3) {
            const int row = sidx[wave][l];        // LDS broadcast per group
            acc += P[(size_t)row * NUM_CLASSES + c];
        }
    }

    const float a1 = __shfl(acc, lane + 20, 64);
    const float a2 = __shfl(acc, lane + 40, 64);

    float v = (lane < NUM_CLASSES) ? (acc + a1 + a2 + bias[c]) : -INFINITY;

    float m = v;
    #pragma unroll
    for (int off = 16; off > 0; off >>= 1)
        m = fmaxf(m, __shfl_xor(m, off, 32));
    const float e = (lane < NUM_CLASSES) ? expf(v - m) : 0.0f;
    float s = e;
    #pragma unroll
    for (int off = 16; off > 0; off >>= 1)
        s += __shfl_xor(s, off, 32);

    if (lane < NUM_CLASSES)
        out[doc * NUM_CLASSES + lane] = e / s;
}

extern "C" void kernel_launch(void* const* d_in, const int* in_sizes, int n_in,
                              void* d_out, int out_size, void* d_ws, size_t ws_size,
                              hipStream_t stream) {
    const float* emb  = (const float*)d_in[0];
    const float* W    = (const float*)d_in[1];
    const float* bias = (const float*)d_in[2];
    const int*   x    = (const int*)d_in[3];
    float* out = (float*)d_out;
    float* P   = (float*)d_ws;   // needs VOCAB*20*4 = 8,000,000 B

    project_kernel<<<K1_GRID, K1_BLOCK, 0, stream>>>(emb, W, P);
    pool_softmax_kernel<<<BATCH / DOCS_PER_BLOCK, K2_BLOCK, 0, stream>>>(P, bias, x, out);
}

// Round 7
// 68.174 us; speedup vs baseline: 38.5349x; 38.5349x over previous
//
#include <hip/hip_runtime.h>
#include <math.h>

#define VOCAB 100000
#define BATCH 4096
#define DOC_LEN 200
#define EMBED_DIM 300
#define NUM_CLASSES 20

// ---------------------------------------------------------------------------
// Kernel 1:  P[v][c] = sum_k emb[v][k] * (W[c][k]/DOC_LEN)
// K-split x R=1: thread = (row, 60-dim slice), 20 accumulators.
//   - waves = 1563 blocks x 5 = 7815 (~30/CU) for latency hiding (r1/r4 lesson)
//   - disjoint K-slices: each emb element loaded exactly ONCE (r3/r4 lesson)
//   - 20 acc + 6 staged float4 ~= 70 VGPR, far from the 128 spill cliff that
//     killed R=2 K-split (r2/r5 lesson)
//   - no address-taken float4s / no runtime-indexed locals (r6 lesson):
//     all lane selection via explicit .x/.y/.z/.w in a macro
//   - W in LDS k-major (r3 lesson: scalar K$ thrash), pre-scaled by 1/200
// ---------------------------------------------------------------------------
#define K1_BLOCK 320
#define K1_RPB   64                                    // rows per block
#define K1_GRID  ((VOCAB + K1_RPB - 1) / K1_RPB)       // 1563

// 4 FMA-steps for one k: uniform ds_read_b128 of W quad + 20 FMAs
#define FMA_K(av, kw)                                                     \
    {                                                                     \
        _Pragma("unroll")                                                 \
        for (int c4 = 0; c4 < NUM_CLASSES; c4 += 4) {                     \
            const float4 w =                                              \
                *reinterpret_cast<const float4*>(&sWT[(kw)][c4]);         \
            acc[c4 + 0] += (av) * w.x;                                    \
            acc[c4 + 1] += (av) * w.y;                                    \
            acc[c4 + 2] += (av) * w.z;                                    \
            acc[c4 + 3] += (av) * w.w;                                    \
        }                                                                 \
    }

__global__ __launch_bounds__(K1_BLOCK) void project_kernel(
    const float* __restrict__ emb,   // (VOCAB, 300)
    const float* __restrict__ W,     // (20, 300)
    float*       __restrict__ P)     // (VOCAB, 20)  [workspace]
{
    // union: sWT [300][20] = 24000 B during compute; partials [5][64][20]
    // = 25600 B afterwards
    __shared__ float smem[5 * K1_RPB * NUM_CLASSES];   // 25600 B
    float (*sWT)[NUM_CLASSES] = reinterpret_cast<float (*)[NUM_CLASSES]>(smem);

    const float inv = 1.0f / (float)DOC_LEN;
    for (int i = threadIdx.x; i < NUM_CLASSES * EMBED_DIM; i += K1_BLOCK) {
        const int c = i / EMBED_DIM;
        const int k = i - c * EMBED_DIM;
        sWT[k][c] = W[i] * inv;                        // fold mean into W
    }
    __syncthreads();

    const int s    = threadIdx.x >> 6;                 // k-slice = wave, 0..4
    const int lane = threadIdx.x & 63;
    const int rbase = blockIdx.x * K1_RPB;
    const int row  = rbase + lane;
    const int rrow = row < VOCAB ? row : VOCAB - 1;    // clamp reads only
    const float* __restrict__ e =
        emb + (size_t)rrow * EMBED_DIM + s * 60;       // this wave's slice

    float acc[NUM_CLASSES];
    #pragma unroll
    for (int c = 0; c < NUM_CLASSES; ++c) acc[c] = 0.0f;

    // 60-dim slice = 5 chunks of 12 floats; 2-deep chunk pipeline.
    float4 a0 = *reinterpret_cast<const float4*>(e + 0);
    float4 a1 = *reinterpret_cast<const float4*>(e + 4);
    float4 a2 = *reinterpret_cast<const float4*>(e + 8);

    #pragma unroll
    for (int kk = 0; kk < 5; ++kk) {
        float4 n0, n1, n2;
        if (kk < 4) {                                  // prefetch next chunk
            const int nk = 12 * (kk + 1);
            n0 = *reinterpret_cast<const float4*>(e + nk);
            n1 = *reinterpret_cast<const float4*>(e + nk + 4);
            n2 = *reinterpret_cast<const float4*>(e + nk + 8);
        }

        const int kb = s * 60 + 12 * kk;               // W row for this chunk
        FMA_K(a0.x, kb + 0)  FMA_K(a0.y, kb + 1)
        FMA_K(a0.z, kb + 2)  FMA_K(a0.w, kb + 3)
        FMA_K(a1.x, kb + 4)  FMA_K(a1.y, kb + 5)
        FMA_K(a1.z, kb + 6)  FMA_K(a1.w, kb + 7)
        FMA_K(a2.x, kb + 8)  FMA_K(a2.y, kb + 9)
        FMA_K(a2.z, kb + 10) FMA_K(a2.w, kb + 11)

        if (kk < 4) { a0 = n0; a1 = n1; a2 = n2; }
    }
    __syncthreads();                                   // done reading sWT

    // partials: [s][lane][20] contiguous; wave64 writes 1280 consecutive B
    float* sPart = smem;
    #pragma unroll
    for (int c = 0; c < NUM_CLASSES; ++c)
        sPart[(s * K1_RPB + lane) * NUM_CLASSES + c] = acc[c];
    __syncthreads();

    // reduce 5 slices: 1280 outputs = 4 per thread, coalesced stores
    #pragma unroll
    for (int j = 0; j < 4; ++j) {
        const int oi = threadIdx.x + j * K1_BLOCK;     // 0..1279 = r*20 + c
        float v = sPart[oi]
                + sPart[1 * K1_RPB * NUM_CLASSES + oi]
                + sPart[2 * K1_RPB * NUM_CLASSES + oi]
                + sPart[3 * K1_RPB * NUM_CLASSES + oi]
                + sPart[4 * K1_RPB * NUM_CLASSES + oi];
        const int gr = rbase + oi / NUM_CLASSES;
        if (gr < VOCAB)
            P[(size_t)rbase * NUM_CLASSES + oi] = v;
    }
}

// ---------------------------------------------------------------------------
// Kernel 2: out[doc] = softmax( sum_l P[x[doc][l]] + b )   (unchanged)
// One wave per doc; 64 lanes = 3 position-groups x 20 classes.
// ---------------------------------------------------------------------------
#define K2_BLOCK 256
#define DOCS_PER_BLOCK 4

__global__ __launch_bounds__(K2_BLOCK) void pool_softmax_kernel(
    const float* __restrict__ P,     // (VOCAB, 20), pre-scaled by 1/DOC_LEN
    const float* __restrict__ bias,  // (20,)
    const int*   __restrict__ x,     // (BATCH, 200)
    float*       __restrict__ out)   // (BATCH, 20)
{
    __shared__ int sidx[DOCS_PER_BLOCK][DOC_LEN];

    const int doc0 = blockIdx.x * DOCS_PER_BLOCK;
    const int tid  = threadIdx.x;

    for (int i = tid; i < DOCS_PER_BLOCK * DOC_LEN; i += K2_BLOCK)
        (&sidx[0][0])[i] = x[doc0 * DOC_LEN + i];
    __syncthreads();

    const int wave = tid >> 6;
    const int lane = tid & 63;
    const int doc  = doc0 + wave;
    const int g    = lane / NUM_CLASSES;          // 0..2 active, 3 idle
    const int c    = lane - g * NUM_CLASSES;

    float acc = 0.0f;
    if (g < 3) {
        #pragma unroll 4
        for (int l = g; l < DOC_LEN; l += 3) {
            const int row = sidx[wave][l];        // LDS broadcast per group
            acc += P[(size_t)row * NUM_CLASSES + c];
        }
    }

    const float a1 = __shfl(acc, lane + 20, 64);
    const float a2 = __shfl(acc, lane + 40, 64);

    float v = (lane < NUM_CLASSES) ? (acc + a1 + a2 + bias[c]) : -INFINITY;

    float m = v;
    #pragma unroll
    for (int off = 16; off > 0; off >>= 1)
        m = fmaxf(m, __shfl_xor(m, off, 32));
    const float e = (lane < NUM_CLASSES) ? expf(v - m) : 0.0f;
    float s = e;
    #pragma unroll
    for (int off = 16; off > 0; off >>= 1)
        s += __shfl_xor(s, off, 32);

    if (lane < NUM_CLASSES)
        out[doc * NUM_CLASSES + lane] = e / s;
}

extern "C" void kernel_launch(void* const* d_in, const int* in_sizes, int n_in,
                              void* d_out, int out_size, void* d_ws, size_t ws_size,
                              hipStream_t stream) {
    const float* emb  = (const float*)d_in[0];
    const float* W    = (const float*)d_in[1];
    const float* bias = (const float*)d_in[2];
    const int*   x    = (const int*)d_in[3];
    float* out = (float*)d_out;
    float* P   = (float*)d_ws;   // needs VOCAB*20*4 = 8,000,000 B

    project_kernel<<<K1_GRID, K1_BLOCK, 0, stream>>>(emb, W, P);
    pool_softmax_kernel<<<BATCH / DOCS_PER_BLOCK, K2_BLOCK, 0, stream>>>(P, bias, x, out);
}